// Round 1
// baseline (225.359 us; speedup 1.0000x reference)
//
#include <hip/hip_runtime.h>
#include <hip/hip_bf16.h>

#define BATCH 256
#define SEQ   512
#define DIM   128
#define LDSK  136   // padded LDS row stride in bf16 elems (272 B: 16B-aligned, bank-shift 4)

typedef __attribute__((ext_vector_type(8))) __bf16  bf16x8;
typedef __attribute__((ext_vector_type(4))) __bf16  bf16x4;
typedef __attribute__((ext_vector_type(4))) float   f32x4;

// ---------------- MFMA layer: acc[RT][8] = X(256xK) @ W^T + bias, wave-private 64/32-row stripe
template<int RT>
__device__ __forceinline__ void matmul_layer(
    const __bf16* __restrict__ Xa, const __bf16* __restrict__ wg,
    const float* __restrict__ bias, f32x4 (&acc)[RT][8], int wave, int m, int q)
{
  const int rowbase = wave * RT * 16;
#pragma unroll
  for (int ct = 0; ct < 8; ++ct) {
    const float b = bias[ct * 16 + m];
    const f32x4 bv = {b, b, b, b};
#pragma unroll
    for (int rt = 0; rt < RT; ++rt) acc[rt][ct] = bv;
  }
#pragma unroll
  for (int ks = 0; ks < 4; ++ks) {
    const int k0 = ks * 32 + q * 8;
    bf16x8 a[RT], bw[8];
#pragma unroll
    for (int rt = 0; rt < RT; ++rt)
      a[rt] = *(const bf16x8*)(Xa + (rowbase + rt * 16 + m) * LDSK + k0);
#pragma unroll
    for (int ct = 0; ct < 8; ++ct)
      bw[ct] = *(const bf16x8*)(wg + (ct * 16 + m) * DIM + k0);
#pragma unroll
    for (int rt = 0; rt < RT; ++rt)
#pragma unroll
      for (int ct = 0; ct < 8; ++ct)
        acc[rt][ct] = __builtin_amdgcn_mfma_f32_16x16x32_bf16(a[rt], bw[ct], acc[rt][ct], 0, 0, 0);
  }
}

template<int RT>
__device__ __forceinline__ void stats_accum(
    const f32x4 (&acc)[RT][8], float* sumA, float* sqA, int m, int q)
{
#pragma unroll
  for (int ct = 0; ct < 8; ++ct) {
    float s = 0.f, ss = 0.f;
#pragma unroll
    for (int rt = 0; rt < RT; ++rt)
#pragma unroll
      for (int r = 0; r < 4; ++r) { const float v = acc[rt][ct][r]; s += v; ss += v * v; }
    s  += __shfl_xor(s, 16, 64);  s  += __shfl_xor(s, 32, 64);
    ss += __shfl_xor(ss, 16, 64); ss += __shfl_xor(ss, 32, 64);
    if (q == 0) { atomicAdd(&sumA[ct * 16 + m], s); atomicAdd(&sqA[ct * 16 + m], ss); }
  }
}

__device__ __forceinline__ void bn_coefs(int tid, const float* __restrict__ g,
    const float* __restrict__ be, float* sumA, float* sqA, float* cA, float* cC)
{
  if (tid < DIM) {
    const float mean = sumA[tid] * (1.0f / BATCH);
    const float var  = sqA[tid]  * (1.0f / BATCH) - mean * mean;
    const float rstd = rsqrtf(var + 1e-5f);
    const float a = g[tid] * rstd;
    cA[tid] = a;
    cC[tid] = be[tid] - a * mean;
    sumA[tid] = 0.f; sqA[tid] = 0.f;   // re-zero for next layer's stats
  }
}

template<int RT>
__device__ __forceinline__ void bn_relu_store(
    const f32x4 (&acc)[RT][8], __bf16* Xa, const float* cA, const float* cC,
    int wave, int m, int q)
{
  const int rowbase = wave * RT * 16;
#pragma unroll
  for (int ct = 0; ct < 8; ++ct) {
    const int n = ct * 16 + m;
    const float a = cA[n], c = cC[n];
#pragma unroll
    for (int rt = 0; rt < RT; ++rt)
#pragma unroll
      for (int r = 0; r < 4; ++r) {
        const float y = fmaxf(0.f, a * acc[rt][ct][r] + c);
        const int row = rowbase + rt * 16 + q * 4 + r;
        Xa[row * LDSK + n] = (__bf16)y;
      }
  }
}

// ---------------- fused MLP kernel: one workgroup = one 256x128 batch problem
template<int NW, bool GATE>
__global__ __launch_bounds__(NW * 64, 2)
void mlp_kernel(const float* __restrict__ xin, long xrow_stride,
                const __bf16* __restrict__ w1, const __bf16* __restrict__ w2,
                const __bf16* __restrict__ w3,
                const float* __restrict__ b1, const float* __restrict__ g1, const float* __restrict__ be1,
                const float* __restrict__ b2, const float* __restrict__ g2, const float* __restrict__ be2,
                const float* __restrict__ b3,
                const float* __restrict__ gate,   // c_out [256*128] when GATE
                float* __restrict__ out)          // GATE: s_out base; else c_out (ws)
{
  const int tid  = threadIdx.x;
  constexpr int NT = NW * 64;
  constexpr int RT = 16 / NW;       // row-tiles (of 16) per wave; 256 rows total
  const int wave = tid >> 6, lane = tid & 63;
  const int m = lane & 15, q = lane >> 4;
  const int slice = GATE ? blockIdx.x : 0;
  const float* x0 = GATE ? (xin + (long)slice * DIM) : xin;

  __shared__ __bf16 Xa[BATCH * LDSK];                 // 69632 B
  __shared__ float sumA[DIM], sqA[DIM], cA[DIM], cC[DIM];

  for (int t = tid; t < DIM; t += NT) { sumA[t] = 0.f; sqA[t] = 0.f; }

  // stage X -> LDS bf16 (coalesced: 32 lanes span one 512B row)
  {
    const int rpi = NT / 32;
    const int r0  = tid >> 5;
    const int c4  = (tid & 31) * 4;
#pragma unroll
    for (int it = 0; it < BATCH / rpi; ++it) {
      const int r = it * rpi + r0;
      const float4 v = *(const float4*)(x0 + (long)r * xrow_stride + c4);
      bf16x4 h = { (__bf16)v.x, (__bf16)v.y, (__bf16)v.z, (__bf16)v.w };
      *(bf16x4*)(Xa + r * LDSK + c4) = h;
    }
  }
  __syncthreads();

  f32x4 acc[RT][8];

  // Layer 1
  matmul_layer<RT>(Xa, w1, b1, acc, wave, m, q);
  stats_accum<RT>(acc, sumA, sqA, m, q);
  __syncthreads();
  bn_coefs(tid, g1, be1, sumA, sqA, cA, cC);
  __syncthreads();
  bn_relu_store<RT>(acc, Xa, cA, cC, wave, m, q);
  __syncthreads();

  // Layer 2
  matmul_layer<RT>(Xa, w2, b2, acc, wave, m, q);
  stats_accum<RT>(acc, sumA, sqA, m, q);
  __syncthreads();
  bn_coefs(tid, g2, be2, sumA, sqA, cA, cC);
  __syncthreads();
  bn_relu_store<RT>(acc, Xa, cA, cC, wave, m, q);
  __syncthreads();

  // Layer 3 + epilogue
  matmul_layer<RT>(Xa, w3, b3, acc, wave, m, q);

  const int rowbase = wave * RT * 16;
#pragma unroll
  for (int ct = 0; ct < 8; ++ct) {
    const int col = ct * 16 + m;
#pragma unroll
    for (int rt = 0; rt < RT; ++rt) {
#pragma unroll
      for (int r = 0; r < 4; ++r) {
        const int row = rowbase + rt * 16 + q * 4 + r;
        float y = acc[rt][ct][r];
        if (GATE) {
          y *= gate[row * DIM + col];
          out[((long)row * SEQ + slice) * DIM + col] = y;
        } else {
          out[row * DIM + col] = y;
        }
      }
    }
  }
}

// ---------------- prep: fp32 weights -> bf16 in ws (6 x 128x128)
__global__ void prep_kernel(const float* __restrict__ w0, const float* __restrict__ w1,
                            const float* __restrict__ w2, const float* __restrict__ w3,
                            const float* __restrict__ w4, const float* __restrict__ w5,
                            __bf16* __restrict__ dst)
{
  const int idx = blockIdx.x * blockDim.x + threadIdx.x;   // 0..24575
  const int mi  = idx >> 12;                                // matrix id (4096 float4 chunks each)
  const int j   = (idx & 4095) * 4;
  const float* srcs[6] = {w0, w1, w2, w3, w4, w5};
  const float4 v = *(const float4*)(srcs[mi] + j);
  bf16x4 h = { (__bf16)v.x, (__bf16)v.y, (__bf16)v.z, (__bf16)v.w };
  *(bf16x4*)(dst + mi * 16384 + j) = h;
}

// ---------------- max over sequence axis: agg[b,d] = max_i s_out[b,i,d]
__global__ __launch_bounds__(512) void maxpool_kernel(
    const float* __restrict__ sout, float* __restrict__ agg)
{
  __shared__ float red[512];
  const int b = blockIdx.x;
  const int t = threadIdx.x;
  const int d = t & 127, ig = t >> 7;
  const float* p = sout + (long)b * SEQ * DIM + d;
  float m0 = -INFINITY, m1 = -INFINITY, m2 = -INFINITY, m3 = -INFINITY;
  const int i0 = ig * 128;
#pragma unroll 8
  for (int i = i0; i < i0 + 128; i += 4) {
    m0 = fmaxf(m0, p[(long)(i + 0) * DIM]);
    m1 = fmaxf(m1, p[(long)(i + 1) * DIM]);
    m2 = fmaxf(m2, p[(long)(i + 2) * DIM]);
    m3 = fmaxf(m3, p[(long)(i + 3) * DIM]);
  }
  red[t] = fmaxf(fmaxf(m0, m1), fmaxf(m2, m3));
  __syncthreads();
  if (t < 128) {
    const float a = fmaxf(fmaxf(red[t], red[t + 128]), fmaxf(red[t + 256], red[t + 384]));
    agg[b * DIM + t] = a;
  }
}

extern "C" void kernel_launch(void* const* d_in, const int* in_sizes, int n_in,
                              void* d_out, int out_size, void* d_ws, size_t ws_size,
                              hipStream_t stream)
{
  const float* s     = (const float*)d_in[0];
  const float* c     = (const float*)d_in[1];
  const float* s_w1  = (const float*)d_in[2];
  const float* s_b1  = (const float*)d_in[3];
  const float* s_g1  = (const float*)d_in[4];
  const float* s_be1 = (const float*)d_in[5];
  const float* s_w2  = (const float*)d_in[6];
  const float* s_b2  = (const float*)d_in[7];
  const float* s_g2  = (const float*)d_in[8];
  const float* s_be2 = (const float*)d_in[9];
  const float* s_w3  = (const float*)d_in[10];
  const float* s_b3  = (const float*)d_in[11];
  const float* c_w1  = (const float*)d_in[12];
  const float* c_b1  = (const float*)d_in[13];
  const float* c_g1  = (const float*)d_in[14];
  const float* c_be1 = (const float*)d_in[15];
  const float* c_w2  = (const float*)d_in[16];
  const float* c_b2  = (const float*)d_in[17];
  const float* c_g2  = (const float*)d_in[18];
  const float* c_be2 = (const float*)d_in[19];
  const float* c_w3  = (const float*)d_in[20];
  const float* c_b3  = (const float*)d_in[21];

  float* out   = (float*)d_out;                         // s_out then aggregated
  float* c_out = (float*)d_ws;                          // 32768 floats
  __bf16* wbf  = (__bf16*)((char*)d_ws + (size_t)BATCH * DIM * sizeof(float));

  // 1) weights fp32 -> bf16 (s_w1,s_w2,s_w3,c_w1,c_w2,c_w3)
  prep_kernel<<<96, 256, 0, stream>>>(s_w1, s_w2, s_w3, c_w1, c_w2, c_w3, wbf);

  // 2) c-path MLP -> c_out (ws), single workgroup of 8 waves
  mlp_kernel<8, false><<<1, 512, 0, stream>>>(
      c, (long)DIM,
      wbf + 3 * 16384, wbf + 4 * 16384, wbf + 5 * 16384,
      c_b1, c_g1, c_be1, c_b2, c_g2, c_be2, c_b3,
      nullptr, c_out);

  // 3) s-path MLP per slice, gated by c_out -> s_out
  mlp_kernel<4, true><<<SEQ, 256, 0, stream>>>(
      s, (long)SEQ * DIM,
      wbf, wbf + 16384, wbf + 2 * 16384,
      s_b1, s_g1, s_be1, s_b2, s_g2, s_be2, s_b3,
      c_out, out);

  // 4) aggregated = max over sequence axis
  maxpool_kernel<<<BATCH, 512, 0, stream>>>(out, out + (long)BATCH * SEQ * DIM);
}